// Round 1
// 305.800 us; speedup vs baseline: 1.0645x; 1.0645x over previous
//
#include <hip/hip_runtime.h>
#include <stdint.h>

// PWC-Net FunctionCorrelation (81 disp) + LeakyReLU(0.1) via bf16 MFMA.
// out[n, dy*9+dx, y, x] = leaky((1/256) Σ_c f1[n,c,y,x] f2p[n,c,y+dy-4,x+dx-4])
//
// Banded-GEMM: per (block y-row wave, dy): D[16m][16n] = A·B^T, K=256.
//   A[m][k] = f1[c0+k, y, x0+m]          (m 0..15; outputs use m<8)
//   B[n][k] = f2p[c0+k, y+dy-4, x0-4+n]  (n 0..15)
//   out(x=x0+m, dx=n-m) valid for m<8, 0<=n-m<=8  (72/256 of tile)
// Block: 8y x 8x outputs, 512 thr (8 waves, wave=y), 8 K-chunks of 32,
// LDS double-buffered bf16 staging, XCD-pinned image (bid&7) + chunk phase.
//
// R5: COALESCED staging. Old maps put the channel index in the fastest lane
// bits -> consecutive lanes 102,400 B apart -> every wave-load = 64 scattered
// 64-B lines (16 B used each); kernel was line-request/MLP bound (MfmaUtil 3%,
// VALU 17%, HBM 11% -- nothing else busy). New maps: lane-fast = x-quad, each
// thread loads a 4-channel group (4 coalesced float4, stride HW) so a
// wave-load = 16 fully-used lines (4x fewer requests, same bytes). The
// 4-channel group makes the two packed k-line words adjacent -> ds_write_b64,
// which lands exactly 2 lanes/bank (conflict-free). LDS layout, fragment
// reads, MFMA loop, epilogue unchanged -> bit-identical output.

constexpr int MAXD = 4;
constexpr int N_ = 8, C_ = 256, H_ = 80, W_ = 160, HW_ = H_ * W_;
constexpr int YT = 8, XT = 8;
constexpr int KC = 32;                  // channels per chunk
constexpr int NCH = C_ / KC;            // 8
constexpr int KLINE = 20;               // words per k-line: 16 data (32 bf16) + 4 pad
constexpr int ROWW  = 16 * KLINE + 8;   // 328 words per m/n-row block (+8 pad)
constexpr int AW    = YT * ROWW;        // 2624 words
constexpr int BWRD  = 16 * ROWW;        // 5248 words
constexpr int BUFW  = AW + BWRD;        // 7872 words = 31488 B per buffer
constexpr int NTHR  = 512;

typedef __attribute__((ext_vector_type(8))) short  frag_ab;   // 8 bf16
typedef __attribute__((ext_vector_type(4))) float  frag_cd;   // 4 fp32

__device__ __forceinline__ uint32_t pkbf(float a, float b) {
    // pack 2 floats -> 2 bf16 (RNE), low half = a (k even)
    uint32_t ua = __float_as_uint(a), ub = __float_as_uint(b);
    ua += 0x7fff + ((ua >> 16) & 1);
    ub += 0x7fff + ((ub >> 16) & 1);
    return (ua >> 16) | (ub & 0xffff0000u);
}

__global__ __launch_bounds__(NTHR, 4)
void corr_mfma_kernel(const float* __restrict__ f1,
                      const float* __restrict__ f2,
                      float* __restrict__ out)
{
    __shared__ uint32_t lds[2 * BUFW];   // 62976 B

    const int t    = threadIdx.x;
    const int wy   = t >> 6;             // wave id = local y (0..7)
    const int lane = t & 63;
    const int nn   = lane & 15;          // MFMA col (n) / frag row id
    const int qq   = lane >> 4;          // quad (k-group / D row group)

    const int bid = blockIdx.x;
    const int img = bid & 7;             // XCD-pinned image
    const int tr  = bid >> 3;            // 0..199
    const int y0  = (tr / 20) * YT;
    const int x0  = (tr % 20) * XT;
    const int phase = img;               // all blocks of an image share chunk order

    const float* f1n = f1 + (size_t)img * C_ * HW_;
    const float* f2n = f2 + (size_t)img * C_ * HW_;

    // ---------- staging maps (per thread, chunk-invariant) ----------
    // B (all 512 threads): x-quad qB (lane-fast, coalesced), channel-quad cqB,
    // source row sB. Thread loads channels c0+4cqB..+3 at (row sB, 4 x's).
    const int qB  = t & 3;                         // x-quad 0..3
    const int cqB = (t >> 2) & 7;                  // channel-quad 0..7
    const int sB  = t >> 5;                        // source row 0..15
    const int ysB = y0 + sB - MAXD;
    const bool rowokB = (unsigned)ysB < (unsigned)H_;
    const int xqB = x0 - MAXD + 4 * qB;            // 16B-aligned (x0%8==0)
    const bool vB = rowokB && (xqB >= 0) && ((xqB + 3) < W_);  // quad fully in/out
    const int offB = (4 * cqB) * HW_ + (rowokB ? ysB * W_ : 0) + (vB ? xqB : 0);
    const int bwrd = AW + sB * ROWW + (4 * qB) * KLINE + 2 * cqB;  // b64 dest (even)

    // A (lanes 0..31 of each wave; wave stages its own y-row):
    // x-quad qA (lane-fast), channel-quad cqA.
    const int qA  = lane & 3;
    const int cqA = (lane >> 2) & 7;
    const int xA  = x0 + 4 * qA;
    const bool vA = (xA + 3) < W_;                 // rows always valid; edge x-tiles pad
    const int offA = (4 * cqA) * HW_ + (y0 + wy) * W_ + (vA ? xA : 0);
    const int awrd = wy * ROWW + (4 * qA) * KLINE + 2 * cqA;       // b64 dest (even)

    // ---------- fragment read offsets (words) — UNCHANGED ----------
    const int afrag_w    = wy * ROWW + nn * KLINE + 4 * qq;        // A: wave's y row
    const int bfrag_base = AW + wy * ROWW + nn * KLINE + 4 * qq;   // + dy*ROWW

    frag_cd acc[9];
#pragma unroll
    for (int d = 0; d < 9; ++d) acc[d] = (frag_cd){0.f, 0.f, 0.f, 0.f};

    float4 ra[4], rb[4];   // 4 channels each (c, c+1, c+2, c+3) at one x-quad

#define LOADS(c0)                                                             \
    {                                                                         \
        const int cb = (c0) * HW_;                                            \
        _Pragma("unroll")                                                     \
        for (int j = 0; j < 4; ++j)                                           \
            rb[j] = vB ? *(const float4*)(f2n + cb + offB + j * HW_)          \
                       : float4{0, 0, 0, 0};                                  \
        if (lane < 32) {                                                      \
            _Pragma("unroll")                                                 \
            for (int j = 0; j < 4; ++j)                                       \
                ra[j] = vA ? *(const float4*)(f1n + cb + offA + j * HW_)      \
                           : float4{0, 0, 0, 0};                              \
        }                                                                     \
    }

#define WRITES(buf)                                                           \
    {                                                                         \
        uint32_t* wp = lds + (buf) * BUFW;                                    \
        const float* b0 = (const float*)&rb[0];                               \
        const float* b1 = (const float*)&rb[1];                               \
        const float* b2 = (const float*)&rb[2];                               \
        const float* b3 = (const float*)&rb[3];                               \
        _Pragma("unroll")                                                     \
        for (int i = 0; i < 4; ++i) {                                         \
            uint2 w;                                                          \
            w.x = pkbf(b0[i], b1[i]);                                         \
            w.y = pkbf(b2[i], b3[i]);                                         \
            *(uint2*)(wp + bwrd + i * KLINE) = w;                             \
        }                                                                     \
        if (lane < 32) {                                                      \
            const float* a0 = (const float*)&ra[0];                           \
            const float* a1 = (const float*)&ra[1];                           \
            const float* a2 = (const float*)&ra[2];                           \
            const float* a3 = (const float*)&ra[3];                           \
            _Pragma("unroll")                                                 \
            for (int i = 0; i < 4; ++i) {                                     \
                uint2 w;                                                      \
                w.x = pkbf(a0[i], a1[i]);                                     \
                w.y = pkbf(a2[i], a3[i]);                                     \
                *(uint2*)(wp + awrd + i * KLINE) = w;                         \
            }                                                                 \
        }                                                                     \
    }

    // prologue: stage first chunk
    LOADS(((phase) & 7) * KC);
    WRITES(0);
    __syncthreads();

    for (int i = 0; i < NCH; ++i) {
        const int p = i & 1;

        // issue next chunk's global loads first (age across the MFMA section)
        if (i + 1 < NCH) LOADS((((i + 1 + phase) & 7) * KC));

        const uint32_t* rp = lds + p * BUFW;
        const frag_ab af = *(const frag_ab*)(rp + afrag_w);
#pragma unroll
        for (int d = 0; d < 9; ++d) {
            const frag_ab bf = *(const frag_ab*)(rp + bfrag_base + d * ROWW);
            acc[d] = __builtin_amdgcn_mfma_f32_16x16x32_bf16(af, bf, acc[d], 0, 0, 0);
        }

        if (i + 1 < NCH) WRITES(1 - p);
        __syncthreads();
    }

    // ---------- epilogue: band extract, scale, leaky, store ----------
    const float inv_c = 1.0f / (float)C_;
    const int y = y0 + wy;
#pragma unroll
    for (int d = 0; d < 9; ++d) {
#pragma unroll
        for (int r = 0; r < 4; ++r) {
            const int m  = 4 * qq + r;        // D row = output x - x0
            const int dx = nn - m;
            if (m < XT && (unsigned)dx <= 8u) {
                float e = acc[d][r] * inv_c;
                e = e > 0.0f ? e : 0.1f * e;
                const int ch = d * 9 + dx;
                out[((size_t)(img * 81 + ch) * H_ + y) * W_ + (x0 + m)] = e;
            }
        }
    }
}

extern "C" void kernel_launch(void* const* d_in, const int* in_sizes, int n_in,
                              void* d_out, int out_size, void* d_ws, size_t ws_size,
                              hipStream_t stream) {
    const float* f1 = (const float*)d_in[0];
    const float* f2 = (const float*)d_in[1];
    float* out = (float*)d_out;
    const int nblocks = N_ * (H_ / YT) * (W_ / XT);  // 8*10*20 = 1600
    corr_mfma_kernel<<<dim3(nblocks), dim3(NTHR), 0, stream>>>(f1, f2, out);
}

// Round 2
// 278.434 us; speedup vs baseline: 1.1691x; 1.0983x over previous
//
#include <hip/hip_runtime.h>
#include <stdint.h>

// PWC-Net FunctionCorrelation (81 disp) + LeakyReLU(0.1) via bf16 MFMA.
// out[n, dy*9+dx, y, x] = leaky((1/256) Σ_c f1[n,c,y,x] f2p[n,c,y+dy-4,x+dx-4])
//
// R6: 16-wide x-tiles. R1 post-mortem: kernel is bound by unique L1-miss
// LINES per CU (~0.1-0.15 lines/cy service rate), not by requests, bytes, or
// any visible pipe (Mfma 3.6 / VALU 24 / HBM 12%). Line traffic per output is
// set by tile halo: 8-wide tiles staged 16 B-x-positions (2 lines) per
// (ch,row) for 8 outputs and wasted half of A. XT=16 makes all 16 MFMA m-rows
// real outputs and amortizes a 24-wide B panel (3 lines) over 16 outputs:
// ~2.7x fewer lines/output, same MFMA total.
//
// Banded-GEMM per (wave=y-row, dy): D[16m][16n] = A·B^T, K=256, TWO n-tiles.
//   A[m][k]  = f1[c0+k, y, x0+m]                 (m 0..15, all used)
//   Bt[n][k] = f2p[c0+k, y+dy-4, x0-4+n+8t]      (panel j=n+8t, j 0..23)
//   out(x=x0+m, dx=j-m) valid 0<=dx<=8; tile0 owns j<16, tile1 owns j>=16.
// Block: 8y x 16x outputs, 512 thr (8 waves), 8 K-chunks of 32 ch,
// LDS 2x40960 B (exactly 2 blocks/CU), XCD-pinned image (bid&7) + chunk phase.

constexpr int MAXD = 4;
constexpr int N_ = 8, C_ = 256, H_ = 80, W_ = 160, HW_ = H_ * W_;
constexpr int YT = 8, XT = 16;
constexpr int KC = 32;                  // channels per chunk
constexpr int NCH = C_ / KC;            // 8
constexpr int KLINE = 20;               // words/k-line: 16 data + 4 pad (b128 align)
constexpr int AROW  = 16 * KLINE;       // 320 words per A y-row (16 m k-lines)
constexpr int BROW  = 24 * KLINE;       // 480 words per B source row (24 j k-lines)
constexpr int ASZ   = YT * AROW;        // 2560 words
constexpr int BSZ   = 16 * BROW;        // 7680 words
constexpr int BUFW  = ASZ + BSZ;        // 10240 words = 40960 B per buffer
constexpr int NTHR  = 512;

typedef __attribute__((ext_vector_type(8))) short  frag_ab;   // 8 bf16
typedef __attribute__((ext_vector_type(4))) float  frag_cd;   // 4 fp32

__device__ __forceinline__ uint32_t pkbf(float a, float b) {
    // pack 2 floats -> 2 bf16 (RNE), low half = a (k even)
    uint32_t ua = __float_as_uint(a), ub = __float_as_uint(b);
    ua += 0x7fff + ((ua >> 16) & 1);
    ub += 0x7fff + ((ub >> 16) & 1);
    return (ua >> 16) | (ub & 0xffff0000u);
}

__global__ __launch_bounds__(NTHR, 4)
void corr_mfma_kernel(const float* __restrict__ f1,
                      const float* __restrict__ f2,
                      float* __restrict__ out)
{
    __shared__ uint32_t lds[2 * BUFW];   // 81920 B = exactly half of 160 KiB

    const int t    = threadIdx.x;
    const int wy   = t >> 6;             // wave id = local y (0..7)
    const int lane = t & 63;
    const int nn   = lane & 15;          // MFMA col (n) / frag row id
    const int qq   = lane >> 4;          // quad (k-group / D row group)

    const int bid = blockIdx.x;
    const int img = bid & 7;             // XCD-pinned image
    const int tr  = bid >> 3;            // 0..99
    const int y0  = (tr / 10) * YT;
    const int x0  = (tr % 10) * XT;      // 0,16,...,144 (line-aligned)
    const int phase = img;

    const float* f1n = f1 + (size_t)img * C_ * HW_;
    const float* f2n = f2 + (size_t)img * C_ * HW_;

    // ---------- staging maps (per thread, chunk-invariant) ----------
    // B1: panel k-lines j 0..15. thread -> x-quad xqB (lane-fast), ch-quad
    // cqB (4 channels, stride HW), source row sB.
    const int xqB = t & 3;
    const int cqB = (t >> 2) & 7;
    const int sB  = t >> 5;                        // 0..15
    const int ysB = y0 + sB - MAXD;
    const bool rokB = (unsigned)ysB < (unsigned)H_;
    const int xB  = x0 - MAXD + 4 * xqB;           // 16B-aligned; quad all-in/out
    const bool vB1 = rokB && (xB >= 0);            // right edge never OOB (<=155)
    const int offB1 = (4 * cqB) * HW_ + (rokB ? ysB * W_ : 0) + (vB1 ? xB : 0);
    const int bwrd1 = ASZ + sB * BROW + (4 * xqB) * KLINE + 2 * cqB;  // b64 dest

    // B2: panel k-lines j 16..23. thread -> x-quad xq2 in {4,5}, ch-PAIR cp2.
    const int xq2 = 4 + (t & 1);
    const int cp2 = (t >> 1) & 15;
    const int s2  = t >> 5;                        // 0..15
    const int ys2 = y0 + s2 - MAXD;
    const bool rok2 = (unsigned)ys2 < (unsigned)H_;
    const int xB2 = x0 - MAXD + 4 * xq2;           // x0+12 / x0+16
    const bool vB2 = rok2 && ((xB2 + 3) < W_);     // left never OOB
    const int offB2 = (2 * cp2) * HW_ + (rok2 ? ys2 * W_ : 0) + (vB2 ? xB2 : 0);
    const int bwrd2 = ASZ + s2 * BROW + (4 * xq2) * KLINE + cp2;      // b32 dest

    // A: thread -> x-quad qA (lane-fast), ch-pair pA, row rA (== wy).
    // XT=16 divides W exactly and rows are always valid -> NO bounds checks.
    const int qA = t & 3;
    const int pA = (t >> 2) & 15;
    const int rA = t >> 6;                         // 0..7
    const int offA = (2 * pA) * HW_ + (y0 + rA) * W_ + (x0 + 4 * qA);
    const int awrd = rA * AROW + (4 * qA) * KLINE + pA;               // b32 dest

    // ---------- fragment read offsets (words) ----------
    const int afrag_w    = wy * AROW + nn * KLINE + 4 * qq;
    const int bfrag_base = ASZ + wy * BROW + nn * KLINE + 4 * qq;  // + d*BROW + 8t*KLINE

    frag_cd acc[9][2];
#pragma unroll
    for (int d = 0; d < 9; ++d) {
        acc[d][0] = (frag_cd){0.f, 0.f, 0.f, 0.f};
        acc[d][1] = (frag_cd){0.f, 0.f, 0.f, 0.f};
    }

    float4 rb1[4], rb2[2], ra[2];

#define LOADS(c0)                                                             \
    {                                                                         \
        const int cb = (c0) * HW_;                                            \
        _Pragma("unroll")                                                     \
        for (int j = 0; j < 4; ++j)                                           \
            rb1[j] = vB1 ? *(const float4*)(f2n + cb + offB1 + j * HW_)       \
                         : float4{0, 0, 0, 0};                                \
        _Pragma("unroll")                                                     \
        for (int j = 0; j < 2; ++j)                                           \
            rb2[j] = vB2 ? *(const float4*)(f2n + cb + offB2 + j * HW_)       \
                         : float4{0, 0, 0, 0};                                \
        _Pragma("unroll")                                                     \
        for (int j = 0; j < 2; ++j)                                           \
            ra[j] = *(const float4*)(f1n + cb + offA + j * HW_);              \
    }

#define WRITES(buf)                                                           \
    {                                                                         \
        uint32_t* wp = lds + (buf) * BUFW;                                    \
        const float* b0 = (const float*)&rb1[0];                              \
        const float* b1 = (const float*)&rb1[1];                              \
        const float* b2 = (const float*)&rb1[2];                              \
        const float* b3 = (const float*)&rb1[3];                              \
        _Pragma("unroll")                                                     \
        for (int i = 0; i < 4; ++i) {                                         \
            uint2 w;                                                          \
            w.x = pkbf(b0[i], b1[i]);                                         \
            w.y = pkbf(b2[i], b3[i]);                                         \
            *(uint2*)(wp + bwrd1 + i * KLINE) = w;                            \
        }                                                                     \
        const float* e0 = (const float*)&rb2[0];                              \
        const float* e1 = (const float*)&rb2[1];                              \
        _Pragma("unroll")                                                     \
        for (int i = 0; i < 4; ++i)                                           \
            wp[bwrd2 + i * KLINE] = pkbf(e0[i], e1[i]);                       \
        const float* a0 = (const float*)&ra[0];                               \
        const float* a1 = (const float*)&ra[1];                               \
        _Pragma("unroll")                                                     \
        for (int i = 0; i < 4; ++i)                                           \
            wp[awrd + i * KLINE] = pkbf(a0[i], a1[i]);                        \
    }

    // prologue: stage first chunk
    LOADS(((phase) & 7) * KC);
    WRITES(0);
    __syncthreads();

    for (int i = 0; i < NCH; ++i) {
        const int p = i & 1;

        // issue next chunk's global loads first (age across the MFMA section)
        if (i + 1 < NCH) LOADS((((i + 1 + phase) & 7) * KC));

        const uint32_t* rp = lds + p * BUFW;
        const frag_ab af = *(const frag_ab*)(rp + afrag_w);
#pragma unroll
        for (int d = 0; d < 9; ++d) {
            const frag_ab bf0 = *(const frag_ab*)(rp + bfrag_base + d * BROW);
            acc[d][0] = __builtin_amdgcn_mfma_f32_16x16x32_bf16(af, bf0, acc[d][0], 0, 0, 0);
            const frag_ab bf1 = *(const frag_ab*)(rp + bfrag_base + d * BROW + 8 * KLINE);
            acc[d][1] = __builtin_amdgcn_mfma_f32_16x16x32_bf16(af, bf1, acc[d][1], 0, 0, 0);
        }

        if (i + 1 < NCH) WRITES(1 - p);
        __syncthreads();
    }

    // ---------- epilogue: band extract, scale, leaky, store ----------
    const float inv_c = 1.0f / (float)C_;
    const int y = y0 + wy;
#pragma unroll
    for (int d = 0; d < 9; ++d) {
#pragma unroll
        for (int tl = 0; tl < 2; ++tl) {
#pragma unroll
            for (int r = 0; r < 4; ++r) {
                const int m  = 4 * qq + r;        // output x - x0 (0..15, all valid)
                const int ng = nn + 8 * tl;       // B panel j
                const int dx = ng - m;
                // tile0 owns j<16 (always), tile1 owns j>=16 (nn>=8)
                if ((tl == 0 || ng >= 16) && (unsigned)dx <= 8u) {
                    float e = acc[d][tl][r] * inv_c;
                    e = e > 0.0f ? e : 0.1f * e;
                    const int ch = d * 9 + dx;
                    out[((size_t)(img * 81 + ch) * H_ + y) * W_ + (x0 + m)] = e;
                }
            }
        }
    }
}

extern "C" void kernel_launch(void* const* d_in, const int* in_sizes, int n_in,
                              void* d_out, int out_size, void* d_ws, size_t ws_size,
                              hipStream_t stream) {
    const float* f1 = (const float*)d_in[0];
    const float* f2 = (const float*)d_in[1];
    float* out = (float*)d_out;
    const int nblocks = N_ * (H_ / YT) * (W_ / XT);  // 8*10*10 = 800
    corr_mfma_kernel<<<dim3(nblocks), dim3(NTHR), 0, stream>>>(f1, f2, out);
}